// Round 4
// baseline (265.011 us; speedup 1.0000x reference)
//
#include <hip/hip_runtime.h>
#include <math.h>
#include <float.h>

// Problem constants (from reference)
#define NPT     16384
#define IN_F    34
#define SDIM    4
#define PDIM    22
#define KNN     8
#define WIDTH   126
#define NCLS    6
#define CH      16     // candidate chunks per query in kNN phase 1
#define ROWS    16     // rows per fused-MLP block
#define TS      256    // kNN LDS tile size (candidates)

// ---------------- workspace layout (bytes), total ~19.5 MB ----------------
#define OFF_RANGES 0
#define OFF_S      256
#define OFF_H      (OFF_S    + NPT*SDIM*4)
#define OFF_PD2    (OFF_H    + NPT*PDIM*4)
#define OFF_PIX    (OFF_PD2  + NPT*CH*KNN*4)
#define OFF_KIDX   (OFF_PIX  + NPT*CH*KNN*4)
#define OFF_KW     (OFF_KIDX + NPT*KNN*4)

// ---------------------------------------------------------
// s = (x@Ws + bs) + 1000*batch ; h = x@Wh + bh  (conv index 1 weights).
// Thread = (row i, slot o): o<4 -> S, o<26 -> H, o==31 -> graph ranges.
__global__ __launch_bounds__(256) void k_sh(const float* __restrict__ x,
                                            const int* __restrict__ batch,
                                            const float* __restrict__ Ws,
                                            const float* __restrict__ bs,
                                            const float* __restrict__ Wh,
                                            const float* __restrict__ bh,
                                            float* __restrict__ S,
                                            float* __restrict__ H,
                                            int* __restrict__ ranges) {
    int t = blockIdx.x * blockDim.x + threadIdx.x;
    int i = t >> 5;
    int o = t & 31;
    if (i >= NPT) return;
    if (o == 31) {  // graph ranges from sorted batch
        int b = batch[i];
        if (i == 0 || batch[i - 1] != b) ranges[b * 2]     = i;
        if (i == NPT - 1 || batch[i + 1] != b) ranges[b * 2 + 1] = i + 1;
        return;
    }
    const float* xr = x + (size_t)i * IN_F;
    if (o < SDIM) {
        float acc = 0.f;
        for (int k = 0; k < IN_F; ++k) acc += xr[k] * Ws[k * SDIM + o];
        S[(size_t)i * SDIM + o] = (acc + bs[o]) + 1000.f * (float)batch[i];
    } else if (o < SDIM + PDIM) {
        int p = o - SDIM;
        float acc = 0.f;
        for (int k = 0; k < IN_F; ++k) acc += xr[k] * Wh[k * PDIM + p];
        H[(size_t)i * PDIM + p] = acc + bh[p];
    }
}

// kNN phase 1, LDS-tiled: block = (256 queries, chunk c). The block's
// candidate window [winlo,winhi) is staged into LDS in tiles; inner loop is
// broadcast ds_read + VALU only. Graph ranges are ordered & disjoint, so
// winlo = thread0's j0, winhi = thread255's j1 covers every thread's window.
// Strict-< insertion in ascending j == jax.lax.top_k tie-breaking.
__global__ __launch_bounds__(256) void k_knn(const float4* __restrict__ S4,
                                             const int* __restrict__ batch,
                                             const int* __restrict__ ranges,
                                             float* __restrict__ PD2,
                                             int* __restrict__ PIX) {
    __shared__ float4 tile[TS];
    __shared__ int s_lo, s_hi;
    const int tid = threadIdx.x;
    const int q   = blockIdx.x * 256 + tid;
    const int c   = blockIdx.y;
    const int b   = batch[q];
    const int gs  = ranges[b * 2];
    const int ge  = ranges[b * 2 + 1];
    const int len = ge - gs;
    const int j0  = gs + (int)(((long long)len * c) / CH);
    const int j1  = gs + (int)(((long long)len * (c + 1)) / CH);
    if (tid == 0)   s_lo = j0;
    if (tid == 255) s_hi = j1;
    __syncthreads();
    const int winlo = s_lo, winhi = s_hi;

    const float4 sq = S4[q];
    float bd[KNN];
    int   bi[KNN];
#pragma unroll
    for (int t = 0; t < KNN; ++t) { bd[t] = FLT_MAX; bi[t] = 0x7fffffff; }

    for (int t0 = winlo; t0 < winhi; t0 += TS) {
        const int nt = (winhi - t0 < TS) ? (winhi - t0) : TS;
        __syncthreads();
        if (tid < nt) tile[tid] = S4[t0 + tid];
        __syncthreads();
        const int lo = (j0 > t0) ? j0 : t0;
        const int hi = (j1 < t0 + nt) ? j1 : (t0 + nt);
#pragma unroll 2
        for (int j = lo; j < hi; ++j) {
            float4 sj = tile[j - t0];
            float d0 = sq.x - sj.x;
            float d1 = sq.y - sj.y;
            float d2 = sq.z - sj.z;
            float d3 = sq.w - sj.w;
            // match reference numerics: rounded squares, sequential sum, no fma
            float dd = __fadd_rn(__fadd_rn(__fadd_rn(__fmul_rn(d0, d0),
                                                     __fmul_rn(d1, d1)),
                                           __fmul_rn(d2, d2)),
                                 __fmul_rn(d3, d3));
            if (dd < bd[KNN - 1]) {
                bd[KNN - 1] = dd;
                bi[KNN - 1] = j;
#pragma unroll
                for (int t = KNN - 1; t >= 1; --t) {
                    if (bd[t] < bd[t - 1]) {
                        float td = bd[t]; bd[t] = bd[t - 1]; bd[t - 1] = td;
                        int   ti = bi[t]; bi[t] = bi[t - 1]; bi[t - 1] = ti;
                    }
                }
            }
        }
    }
    // transposed partial layout -> coalesced writes here, coalesced reads in merge
    const size_t base = ((size_t)c * NPT + q) * KNN;
#pragma unroll
    for (int t = 0; t < KNN; ++t) { PD2[base + t] = bd[t]; PIX[base + t] = bi[t]; }
}

// kNN phase 2: merge CH partial top-8 lists. Lexicographic (d2, idx) strict
// comparison is a total order -> scan order irrelevant, matches top_k ties.
__global__ __launch_bounds__(64) void k_merge(const float* __restrict__ PD2,
                                              const int* __restrict__ PIX,
                                              int* __restrict__ KIDX,
                                              float* __restrict__ KW) {
    int q = blockIdx.x * blockDim.x + threadIdx.x;
    if (q >= NPT) return;
    float bd[KNN];
    int   bi[KNN];
#pragma unroll
    for (int t = 0; t < KNN; ++t) { bd[t] = FLT_MAX; bi[t] = 0x7fffffff; }
    for (int cc = 0; cc < CH; ++cc) {
        const size_t base = ((size_t)cc * NPT + q) * KNN;
#pragma unroll
        for (int e = 0; e < KNN; ++e) {
            float dd = PD2[base + e];
            int   jj = PIX[base + e];
            if (dd < bd[KNN - 1] || (dd == bd[KNN - 1] && jj < bi[KNN - 1])) {
                bd[KNN - 1] = dd;
                bi[KNN - 1] = jj;
#pragma unroll
                for (int t = KNN - 1; t >= 1; --t) {
                    bool sw = (bd[t] < bd[t - 1]) ||
                              (bd[t] == bd[t - 1] && bi[t] < bi[t - 1]);
                    if (sw) {
                        float td = bd[t]; bd[t] = bd[t - 1]; bd[t - 1] = td;
                        int   ti = bi[t]; bi[t] = bi[t - 1]; bi[t - 1] = ti;
                    }
                }
            }
        }
    }
#pragma unroll
    for (int t = 0; t < KNN; ++t) {
        KIDX[(size_t)q * KNN + t] = bi[t];
        KW[(size_t)q * KNN + t]   = expf(-10.f * bd[t]);
    }
}

// Fused: gather/aggregate -> emb -> MLP(3 layers) -> out
// Block: 256 threads = 16 rows x 16 out-chunks; activations staged in LDS.
// acc arrays kept <=8 wide and k-loops unroll-bounded to avoid VGPR spills.
__global__ __launch_bounds__(256) void k_fused(const float* __restrict__ x,
                                               const float* __restrict__ H,
                                               const int* __restrict__ KIDX,
                                               const float* __restrict__ KW,
                                               const float* __restrict__ Wo1,
                                               const float* __restrict__ Wo2,
                                               const float* __restrict__ bo2,
                                               const float* __restrict__ W1,
                                               const float* __restrict__ b1,
                                               const float* __restrict__ W2,
                                               const float* __restrict__ b2,
                                               const float* __restrict__ W3,
                                               const float* __restrict__ b3,
                                               float* __restrict__ out) {
    __shared__ float xt[ROWS * IN_F];          // 16x34
    __shared__ float aggt[ROWS * 2 * PDIM];    // 16x44 : [mean(22) | max(22)]
    __shared__ float et[ROWS * IN_F];          // 16x34
    __shared__ float h1t[ROWS * WIDTH];        // 16x126
    __shared__ float h2t[ROWS * WIDTH];        // 16x126  (total 23.3 KB)

    const int tid  = threadIdx.x;
    const int row0 = blockIdx.x * ROWS;
    const int r    = tid >> 4;     // 0..15
    const int c    = tid & 15;     // 0..15
    const int gi   = row0 + r;

    // stage x tile (coalesced)
    for (int t = tid; t < ROWS * IN_F; t += 256)
        xt[t] = x[(size_t)row0 * IN_F + t];

    // gather + aggregate: lane c<11 handles dims {c, c+11}
    if (c < 11) {
        const int p0 = c, p1 = c + 11;
        float s0 = 0.f, s1 = 0.f;
        float m0 = -FLT_MAX, m1 = -FLT_MAX;
#pragma unroll
        for (int k = 0; k < KNN; ++k) {
            int   j = KIDX[(size_t)gi * KNN + k];
            float w = KW[(size_t)gi * KNN + k];
            const float* hr = H + (size_t)j * PDIM;
            float v0 = hr[p0] * w; s0 += v0; m0 = fmaxf(m0, v0);
            float v1 = hr[p1] * w; s1 += v1; m1 = fmaxf(m1, v1);
        }
        aggt[r * 44 + p0] = s0 * 0.125f; aggt[r * 44 + PDIM + p0] = m0;
        aggt[r * 44 + p1] = s1 * 0.125f; aggt[r * 44 + PDIM + p1] = m1;
    }
    __syncthreads();

    // et = x@Wo1 + agg@Wo2 + bo2 ; 3-wide chunks, j0=min(3c,31); overlap
    // lanes write bitwise-identical duplicates (benign)
    {
        const int j0 = (3 * c < 31) ? 3 * c : 31;
        float acc[3] = {0.f, 0.f, 0.f};
        const float* ar = xt + r * IN_F;
#pragma unroll 4
        for (int k = 0; k < IN_F; ++k) {
            float av = ar[k];
            const float* wr = Wo1 + k * IN_F + j0;
#pragma unroll
            for (int jj = 0; jj < 3; ++jj) acc[jj] += av * wr[jj];
        }
        const float* gr = aggt + r * 44;
#pragma unroll 4
        for (int p = 0; p < 2 * PDIM; ++p) {
            float av = gr[p];
            const float* wr = Wo2 + p * IN_F + j0;
#pragma unroll
            for (int jj = 0; jj < 3; ++jj) acc[jj] += av * wr[jj];
        }
#pragma unroll
        for (int jj = 0; jj < 3; ++jj)
            et[r * IN_F + j0 + jj] = acc[jj] + bo2[j0 + jj];
    }
    __syncthreads();

    // h1 = elu(et@W1 + b1) ; 8-wide chunks, j0=min(8c,118)
    {
        const int j0 = (8 * c < 118) ? 8 * c : 118;
        float acc[8] = {0.f, 0.f, 0.f, 0.f, 0.f, 0.f, 0.f, 0.f};
        const float* ar = et + r * IN_F;
#pragma unroll 4
        for (int k = 0; k < IN_F; ++k) {
            float av = ar[k];
            const float* wr = W1 + k * WIDTH + j0;
#pragma unroll
            for (int jj = 0; jj < 8; ++jj) acc[jj] += av * wr[jj];
        }
#pragma unroll
        for (int jj = 0; jj < 8; ++jj) {
            float v = acc[jj] + b1[j0 + jj];
            h1t[r * WIDTH + j0 + jj] = v > 0.f ? v : expm1f(v);
        }
    }
    __syncthreads();

    // h2 = elu(h1@W2 + b2)
    {
        const int j0 = (8 * c < 118) ? 8 * c : 118;
        float acc[8] = {0.f, 0.f, 0.f, 0.f, 0.f, 0.f, 0.f, 0.f};
        const float* ar = h1t + r * WIDTH;
#pragma unroll 4
        for (int k = 0; k < WIDTH; ++k) {
            float av = ar[k];
            const float* wr = W2 + k * WIDTH + j0;
#pragma unroll
            for (int jj = 0; jj < 8; ++jj) acc[jj] += av * wr[jj];
        }
#pragma unroll
        for (int jj = 0; jj < 8; ++jj) {
            float v = acc[jj] + b2[j0 + jj];
            h2t[r * WIDTH + j0 + jj] = v > 0.f ? v : expm1f(v);
        }
    }
    __syncthreads();

    // out = h2@W3 + b3 ; lane c<6 computes one class
    if (c < NCLS) {
        float acc = 0.f;
        const float* ar = h2t + r * WIDTH;
#pragma unroll 4
        for (int k = 0; k < WIDTH; ++k) acc += ar[k] * W3[k * NCLS + c];
        out[(size_t)gi * NCLS + c] = acc + b3[c];
    }
}

extern "C" void kernel_launch(void* const* d_in, const int* in_sizes, int n_in,
                              void* d_out, int out_size, void* d_ws, size_t ws_size,
                              hipStream_t stream) {
    const float* x     = (const float*)d_in[0];
    const int*   batch = (const int*)d_in[1];
    // Only conv index NCONV-1 == 1 affects the output (loop discards earlier)
    const float* Ws  = (const float*)d_in[2] + IN_F * SDIM;
    const float* bs  = (const float*)d_in[3] + SDIM;
    const float* Wh  = (const float*)d_in[4] + IN_F * PDIM;
    const float* bh  = (const float*)d_in[5] + PDIM;
    const float* Wo1 = (const float*)d_in[6] + IN_F * IN_F;
    const float* Wo2 = (const float*)d_in[7] + 2 * PDIM * IN_F;
    const float* bo2 = (const float*)d_in[8] + IN_F;
    const float* W1  = (const float*)d_in[9];
    const float* b1  = (const float*)d_in[10];
    const float* W2  = (const float*)d_in[11];
    const float* b2  = (const float*)d_in[12];
    const float* W3  = (const float*)d_in[13];
    const float* b3  = (const float*)d_in[14];
    float* out = (float*)d_out;

    char* ws = (char*)d_ws;
    int*   ranges = (int*)(ws + OFF_RANGES);
    float* S      = (float*)(ws + OFF_S);
    float* H      = (float*)(ws + OFF_H);
    float* PD2    = (float*)(ws + OFF_PD2);
    int*   PIX    = (int*)(ws + OFF_PIX);
    int*   KIDX   = (int*)(ws + OFF_KIDX);
    float* KW     = (float*)(ws + OFF_KW);

    k_sh<<<dim3(NPT * 32 / 256), dim3(256), 0, stream>>>(x, batch, Ws, bs, Wh, bh, S, H, ranges);
    k_knn<<<dim3(NPT / 256, CH), dim3(256), 0, stream>>>((const float4*)S, batch, ranges, PD2, PIX);
    k_merge<<<dim3(NPT / 64), dim3(64), 0, stream>>>(PD2, PIX, KIDX, KW);
    k_fused<<<dim3(NPT / ROWS), dim3(256), 0, stream>>>(x, H, KIDX, KW, Wo1, Wo2, bo2,
                                                        W1, b1, W2, b2, W3, b3, out);
}

// Round 5
// 208.945 us; speedup vs baseline: 1.2683x; 1.2683x over previous
//
#include <hip/hip_runtime.h>
#include <math.h>
#include <float.h>

// Problem constants (from reference)
#define NPT     16384
#define IN_F    34
#define SDIM    4
#define PDIM    22
#define KNN     8
#define WIDTH   126
#define NCLS    6
#define CH      16     // candidate chunks per query in kNN phase 1
#define ROWS    16     // rows per fused-MLP block

typedef unsigned long long u64;

// ---------------- workspace layout (bytes), total ~19.5 MB ----------------
#define OFF_RANGES 0
#define OFF_S      256
#define OFF_H      (OFF_S  + NPT*SDIM*4)
#define OFF_PK     (OFF_H  + NPT*PDIM*4)
#define OFF_KIDX   (OFF_PK + (size_t)NPT*CH*KNN*8)
#define OFF_KW     (OFF_KIDX + NPT*KNN*4)

// key = (float_bits(d2) << 32) | j : u64 order == lex (d2, idx) order, which is
// exactly jax.lax.top_k's tie-breaking. d2 >= 0 so float bits are monotone.
#define INITK ((((u64)0x7f7fffffu) << 32) | 0xffffffffu)

__device__ __forceinline__ void key_insert(u64 key, u64* u) {
#pragma unroll
    for (int t = 0; t < KNN; ++t) {
        bool lt = key < u[t];
        u64 mn = lt ? key  : u[t];
        u64 mx = lt ? u[t] : key;
        u[t] = mn;
        key  = mx;
    }
}

// match reference numerics: rounded squares, sequential sum, no fma
__device__ __forceinline__ float dist2(const float4 a, const float4 b) {
    float d0 = a.x - b.x;
    float d1 = a.y - b.y;
    float d2 = a.z - b.z;
    float d3 = a.w - b.w;
    return __fadd_rn(__fadd_rn(__fadd_rn(__fmul_rn(d0, d0),
                                         __fmul_rn(d1, d1)),
                               __fmul_rn(d2, d2)),
                     __fmul_rn(d3, d3));
}

// ---------------------------------------------------------
// s = (x@Ws + bs) + 1000*batch ; h = x@Wh + bh  (conv index 1 weights).
// Thread = (row i, slot o): o<4 -> S, o<26 -> H, o==31 -> graph ranges.
__global__ __launch_bounds__(256) void k_sh(const float* __restrict__ x,
                                            const int* __restrict__ batch,
                                            const float* __restrict__ Ws,
                                            const float* __restrict__ bs,
                                            const float* __restrict__ Wh,
                                            const float* __restrict__ bh,
                                            float* __restrict__ S,
                                            float* __restrict__ H,
                                            int* __restrict__ ranges) {
    int t = blockIdx.x * blockDim.x + threadIdx.x;
    int i = t >> 5;
    int o = t & 31;
    if (i >= NPT) return;
    if (o == 31) {  // graph ranges from sorted batch
        int b = batch[i];
        if (i == 0 || batch[i - 1] != b) ranges[b * 2]     = i;
        if (i == NPT - 1 || batch[i + 1] != b) ranges[b * 2 + 1] = i + 1;
        return;
    }
    const float* xr = x + (size_t)i * IN_F;
    if (o < SDIM) {
        float acc = 0.f;
        for (int k = 0; k < IN_F; ++k) acc += xr[k] * Ws[k * SDIM + o];
        S[(size_t)i * SDIM + o] = (acc + bs[o]) + 1000.f * (float)batch[i];
    } else if (o < SDIM + PDIM) {
        int p = o - SDIM;
        float acc = 0.f;
        for (int k = 0; k < IN_F; ++k) acc += xr[k] * Wh[k * PDIM + p];
        H[(size_t)i * PDIM + p] = acc + bh[p];
    }
}

// kNN phase 1: thread = (query pair, chunk c). Global candidate loads are
// wave-uniform -> L1 broadcast (LDS staging measurably hurt; round-4 lesson).
// Branchless u64-key compare-exchange top-8: in a 128-candidate chunk some
// lane inserts nearly every iteration, so the branch was pure overhead.
__global__ __launch_bounds__(256) void k_knn(const float4* __restrict__ S4,
                                             const int* __restrict__ batch,
                                             const int* __restrict__ ranges,
                                             u64* __restrict__ PK) {
    const int tid = threadIdx.x;
    const int qp  = blockIdx.x * 256 + tid;
    const int q0  = qp * 2, q1 = q0 + 1;
    const int c   = blockIdx.y;
    const int b0  = batch[q0], b1 = batch[q1];
    const float4 sa = S4[q0];
    const float4 sb = S4[q1];
    u64 ua[KNN], ub[KNN];
#pragma unroll
    for (int t = 0; t < KNN; ++t) { ua[t] = INITK; ub[t] = INITK; }

    const int gs0  = ranges[b0 * 2];
    const int len0 = ranges[b0 * 2 + 1] - gs0;
    const int ja0  = gs0 + (int)(((long long)len0 * c) / CH);
    const int ja1  = gs0 + (int)(((long long)len0 * (c + 1)) / CH);

    if (b0 == b1) {  // common case: both queries share the candidate window
#pragma unroll 2
        for (int j = ja0; j < ja1; ++j) {
            float4 sj = S4[j];
            float da = dist2(sa, sj);
            float db = dist2(sb, sj);
            key_insert(((u64)__float_as_uint(da) << 32) | (unsigned)j, ua);
            key_insert(((u64)__float_as_uint(db) << 32) | (unsigned)j, ub);
        }
    } else {         // rare: pair straddles a graph boundary
        for (int j = ja0; j < ja1; ++j) {
            float4 sj = S4[j];
            key_insert(((u64)__float_as_uint(dist2(sa, sj)) << 32) | (unsigned)j, ua);
        }
        const int gs1  = ranges[b1 * 2];
        const int len1 = ranges[b1 * 2 + 1] - gs1;
        const int jb0  = gs1 + (int)(((long long)len1 * c) / CH);
        const int jb1  = gs1 + (int)(((long long)len1 * (c + 1)) / CH);
        for (int j = jb0; j < jb1; ++j) {
            float4 sj = S4[j];
            key_insert(((u64)__float_as_uint(dist2(sb, sj)) << 32) | (unsigned)j, ub);
        }
    }
    // [c][q][t] layout; q1 = q0+1 -> contiguous 128B per thread
    const size_t base = ((size_t)c * NPT + q0) * KNN;
#pragma unroll
    for (int t = 0; t < KNN; ++t) {
        PK[base + t]       = ua[t];
        PK[base + KNN + t] = ub[t];
    }
}

// kNN phase 2: 2 threads per query, each branchless-merges half the chunks,
// then combine via LDS. u64 keys form a total order -> any merge order is
// exact; final unpack gives KIDX + w = exp(-10*d2). Order of the 8 is
// irrelevant downstream (mean/max are permutation-invariant).
__global__ __launch_bounds__(256) void k_merge(const u64* __restrict__ PK,
                                               int* __restrict__ KIDX,
                                               float* __restrict__ KW) {
    __shared__ u64 lds[128 * KNN];
    const int tid = threadIdx.x;
    const int r   = tid >> 1;
    const int h   = tid & 1;
    const int q   = blockIdx.x * 128 + r;
    u64 u[KNN];
#pragma unroll
    for (int t = 0; t < KNN; ++t) u[t] = INITK;
    for (int cc = h * (CH / 2); cc < (h + 1) * (CH / 2); ++cc) {
        const size_t base = ((size_t)cc * NPT + q) * KNN;
#pragma unroll
        for (int e = 0; e < KNN; ++e) key_insert(PK[base + e], u);
    }
    if (h == 1) {
#pragma unroll
        for (int t = 0; t < KNN; ++t) lds[r * KNN + t] = u[t];
    }
    __syncthreads();
    if (h == 0) {
#pragma unroll
        for (int e = 0; e < KNN; ++e) key_insert(lds[r * KNN + e], u);
#pragma unroll
        for (int t = 0; t < KNN; ++t) {
            float d = __uint_as_float((unsigned)(u[t] >> 32));
            KIDX[(size_t)q * KNN + t] = (int)(unsigned)(u[t] & 0xffffffffu);
            KW[(size_t)q * KNN + t]   = expf(-10.f * d);
        }
    }
}

// Fused: gather/aggregate -> emb -> MLP(3 layers) -> out
// Block: 256 threads = 16 rows x 16 out-chunks; activations staged in LDS.
// acc arrays kept <=8 wide and k-loops unroll-bounded to avoid VGPR spills.
__global__ __launch_bounds__(256) void k_fused(const float* __restrict__ x,
                                               const float* __restrict__ H,
                                               const int* __restrict__ KIDX,
                                               const float* __restrict__ KW,
                                               const float* __restrict__ Wo1,
                                               const float* __restrict__ Wo2,
                                               const float* __restrict__ bo2,
                                               const float* __restrict__ W1,
                                               const float* __restrict__ b1,
                                               const float* __restrict__ W2,
                                               const float* __restrict__ b2,
                                               const float* __restrict__ W3,
                                               const float* __restrict__ b3,
                                               float* __restrict__ out) {
    __shared__ float xt[ROWS * IN_F];          // 16x34
    __shared__ float aggt[ROWS * 2 * PDIM];    // 16x44 : [mean(22) | max(22)]
    __shared__ float et[ROWS * IN_F];          // 16x34
    __shared__ float h1t[ROWS * WIDTH];        // 16x126
    __shared__ float h2t[ROWS * WIDTH];        // 16x126  (total 23.3 KB)

    const int tid  = threadIdx.x;
    const int row0 = blockIdx.x * ROWS;
    const int r    = tid >> 4;     // 0..15
    const int c    = tid & 15;     // 0..15
    const int gi   = row0 + r;

    // stage x tile (coalesced)
    for (int t = tid; t < ROWS * IN_F; t += 256)
        xt[t] = x[(size_t)row0 * IN_F + t];

    // gather + aggregate: lane c<11 handles dims {c, c+11}
    if (c < 11) {
        const int p0 = c, p1 = c + 11;
        float s0 = 0.f, s1 = 0.f;
        float m0 = -FLT_MAX, m1 = -FLT_MAX;
#pragma unroll
        for (int k = 0; k < KNN; ++k) {
            int   j = KIDX[(size_t)gi * KNN + k];
            float w = KW[(size_t)gi * KNN + k];
            const float* hr = H + (size_t)j * PDIM;
            float v0 = hr[p0] * w; s0 += v0; m0 = fmaxf(m0, v0);
            float v1 = hr[p1] * w; s1 += v1; m1 = fmaxf(m1, v1);
        }
        aggt[r * 44 + p0] = s0 * 0.125f; aggt[r * 44 + PDIM + p0] = m0;
        aggt[r * 44 + p1] = s1 * 0.125f; aggt[r * 44 + PDIM + p1] = m1;
    }
    __syncthreads();

    // et = x@Wo1 + agg@Wo2 + bo2 ; 3-wide chunks, j0=min(3c,31); overlap
    // lanes write bitwise-identical duplicates (benign)
    {
        const int j0 = (3 * c < 31) ? 3 * c : 31;
        float acc[3] = {0.f, 0.f, 0.f};
        const float* ar = xt + r * IN_F;
#pragma unroll 4
        for (int k = 0; k < IN_F; ++k) {
            float av = ar[k];
            const float* wr = Wo1 + k * IN_F + j0;
#pragma unroll
            for (int jj = 0; jj < 3; ++jj) acc[jj] += av * wr[jj];
        }
        const float* gr = aggt + r * 44;
#pragma unroll 4
        for (int p = 0; p < 2 * PDIM; ++p) {
            float av = gr[p];
            const float* wr = Wo2 + p * IN_F + j0;
#pragma unroll
            for (int jj = 0; jj < 3; ++jj) acc[jj] += av * wr[jj];
        }
#pragma unroll
        for (int jj = 0; jj < 3; ++jj)
            et[r * IN_F + j0 + jj] = acc[jj] + bo2[j0 + jj];
    }
    __syncthreads();

    // h1 = elu(et@W1 + b1) ; 8-wide chunks, j0=min(8c,118)
    {
        const int j0 = (8 * c < 118) ? 8 * c : 118;
        float acc[8] = {0.f, 0.f, 0.f, 0.f, 0.f, 0.f, 0.f, 0.f};
        const float* ar = et + r * IN_F;
#pragma unroll 4
        for (int k = 0; k < IN_F; ++k) {
            float av = ar[k];
            const float* wr = W1 + k * WIDTH + j0;
#pragma unroll
            for (int jj = 0; jj < 8; ++jj) acc[jj] += av * wr[jj];
        }
#pragma unroll
        for (int jj = 0; jj < 8; ++jj) {
            float v = acc[jj] + b1[j0 + jj];
            h1t[r * WIDTH + j0 + jj] = v > 0.f ? v : expm1f(v);
        }
    }
    __syncthreads();

    // h2 = elu(h1@W2 + b2)
    {
        const int j0 = (8 * c < 118) ? 8 * c : 118;
        float acc[8] = {0.f, 0.f, 0.f, 0.f, 0.f, 0.f, 0.f, 0.f};
        const float* ar = h1t + r * WIDTH;
#pragma unroll 4
        for (int k = 0; k < WIDTH; ++k) {
            float av = ar[k];
            const float* wr = W2 + k * WIDTH + j0;
#pragma unroll
            for (int jj = 0; jj < 8; ++jj) acc[jj] += av * wr[jj];
        }
#pragma unroll
        for (int jj = 0; jj < 8; ++jj) {
            float v = acc[jj] + b2[j0 + jj];
            h2t[r * WIDTH + j0 + jj] = v > 0.f ? v : expm1f(v);
        }
    }
    __syncthreads();

    // out = h2@W3 + b3 ; lane c<6 computes one class
    if (c < NCLS) {
        float acc = 0.f;
        const float* ar = h2t + r * WIDTH;
#pragma unroll 4
        for (int k = 0; k < WIDTH; ++k) acc += ar[k] * W3[k * NCLS + c];
        out[(size_t)gi * NCLS + c] = acc + b3[c];
    }
}

extern "C" void kernel_launch(void* const* d_in, const int* in_sizes, int n_in,
                              void* d_out, int out_size, void* d_ws, size_t ws_size,
                              hipStream_t stream) {
    const float* x     = (const float*)d_in[0];
    const int*   batch = (const int*)d_in[1];
    // Only conv index NCONV-1 == 1 affects the output (loop discards earlier)
    const float* Ws  = (const float*)d_in[2] + IN_F * SDIM;
    const float* bs  = (const float*)d_in[3] + SDIM;
    const float* Wh  = (const float*)d_in[4] + IN_F * PDIM;
    const float* bh  = (const float*)d_in[5] + PDIM;
    const float* Wo1 = (const float*)d_in[6] + IN_F * IN_F;
    const float* Wo2 = (const float*)d_in[7] + 2 * PDIM * IN_F;
    const float* bo2 = (const float*)d_in[8] + IN_F;
    const float* W1  = (const float*)d_in[9];
    const float* b1  = (const float*)d_in[10];
    const float* W2  = (const float*)d_in[11];
    const float* b2  = (const float*)d_in[12];
    const float* W3  = (const float*)d_in[13];
    const float* b3  = (const float*)d_in[14];
    float* out = (float*)d_out;

    char* ws = (char*)d_ws;
    int*   ranges = (int*)(ws + OFF_RANGES);
    float* S      = (float*)(ws + OFF_S);
    float* H      = (float*)(ws + OFF_H);
    u64*   PK     = (u64*)(ws + OFF_PK);
    int*   KIDX   = (int*)(ws + OFF_KIDX);
    float* KW     = (float*)(ws + OFF_KW);

    k_sh<<<dim3(NPT * 32 / 256), dim3(256), 0, stream>>>(x, batch, Ws, bs, Wh, bh, S, H, ranges);
    k_knn<<<dim3(NPT / 512, CH), dim3(256), 0, stream>>>((const float4*)S, batch, ranges, PK);
    k_merge<<<dim3(NPT / 128), dim3(256), 0, stream>>>(PK, KIDX, KW);
    k_fused<<<dim3(NPT / ROWS), dim3(256), 0, stream>>>(x, H, KIDX, KW, Wo1, Wo2, bo2,
                                                        W1, b1, W2, b2, W3, b3, out);
}

// Round 6
// 169.659 us; speedup vs baseline: 1.5620x; 1.2316x over previous
//
#include <hip/hip_runtime.h>
#include <math.h>
#include <float.h>

// Problem constants (from reference)
#define NPT     16384
#define IN_F    34
#define SDIM    4
#define PDIM    22
#define KNN     8
#define WIDTH   126
#define NCLS    6
#define ROWS    16     // rows per fused-MLP block

typedef unsigned long long u64;

// ---------------- workspace layout (bytes), total ~3 MB ----------------
#define OFF_RANGES 0
#define OFF_S      256
#define OFF_H      (OFF_S  + NPT*SDIM*4)
#define OFF_KIDX   (OFF_H  + NPT*PDIM*4)
#define OFF_KW     (OFF_KIDX + NPT*KNN*4)

// key = (float_bits(d2) << 32) | j : u64 order == lex (d2, idx) order, which is
// exactly jax.lax.top_k's tie-breaking. d2 >= 0 so float bits are monotone.
#define INITK ((((u64)0x7f7fffffu) << 32) | 0xffffffffu)

__device__ __forceinline__ void key_insert(u64 key, u64* u) {
#pragma unroll
    for (int t = 0; t < KNN; ++t) {
        bool lt = key < u[t];
        u64 mn = lt ? key  : u[t];
        u64 mx = lt ? u[t] : key;
        u[t] = mn;
        key  = mx;
    }
}

// match reference numerics: rounded squares, sequential sum, no fma
__device__ __forceinline__ float dist2(const float4 a, const float4 b) {
    float d0 = a.x - b.x;
    float d1 = a.y - b.y;
    float d2 = a.z - b.z;
    float d3 = a.w - b.w;
    return __fadd_rn(__fadd_rn(__fadd_rn(__fmul_rn(d0, d0),
                                         __fmul_rn(d1, d1)),
                               __fmul_rn(d2, d2)),
                     __fmul_rn(d3, d3));
}

// ---------------------------------------------------------
// s = (x@Ws + bs) + 1000*batch ; h = x@Wh + bh  (conv index 1 weights).
// Thread = (row i, slot o): o<4 -> S, o<26 -> H, o==31 -> graph ranges.
__global__ __launch_bounds__(256) void k_sh(const float* __restrict__ x,
                                            const int* __restrict__ batch,
                                            const float* __restrict__ Ws,
                                            const float* __restrict__ bs,
                                            const float* __restrict__ Wh,
                                            const float* __restrict__ bh,
                                            float* __restrict__ S,
                                            float* __restrict__ H,
                                            int* __restrict__ ranges) {
    int t = blockIdx.x * blockDim.x + threadIdx.x;
    int i = t >> 5;
    int o = t & 31;
    if (i >= NPT) return;
    if (o == 31) {  // graph ranges from sorted batch
        int b = batch[i];
        if (i == 0 || batch[i - 1] != b) ranges[b * 2]     = i;
        if (i == NPT - 1 || batch[i + 1] != b) ranges[b * 2 + 1] = i + 1;
        return;
    }
    const float* xr = x + (size_t)i * IN_F;
    if (o < SDIM) {
        float acc = 0.f;
        for (int k = 0; k < IN_F; ++k) acc += xr[k] * Ws[k * SDIM + o];
        S[(size_t)i * SDIM + o] = (acc + bs[o]) + 1000.f * (float)batch[i];
    } else if (o < SDIM + PDIM) {
        int p = o - SDIM;
        float acc = 0.f;
        for (int k = 0; k < IN_F; ++k) acc += xr[k] * Wh[k * PDIM + p];
        H[(size_t)i * PDIM + p] = acc + bh[p];
    }
}

// Fused kNN: 32 lanes per query (8 queries per 256-thread block, grid 2048 ->
// 8 waves/SIMD; round-5's 2 waves/SIMD exposed the insert-chain latency).
// Each lane scans len/32 candidates keeping a branchless u64-key top-8, then a
// 5-step __shfl_xor butterfly (width 32) merges the 32 lists in-register --
// exact under the u64 total order. Lane 0 writes final KIDX + w=exp(-10*d2).
// No intermediate global traffic, no separate merge kernel.
__global__ __launch_bounds__(256, 8) void k_knn(const float4* __restrict__ S4,
                                                const int* __restrict__ batch,
                                                const int* __restrict__ ranges,
                                                int* __restrict__ KIDX,
                                                float* __restrict__ KW) {
    const int tid = threadIdx.x;
    const int q   = blockIdx.x * 8 + (tid >> 5);
    const int t   = tid & 31;
    const int b   = batch[q];
    const int gs  = ranges[b * 2];
    const int len = ranges[b * 2 + 1] - gs;
    const int j0  = gs + (int)(((long long)len * t) >> 5);
    const int j1  = gs + (int)(((long long)len * (t + 1)) >> 5);
    const float4 sq = S4[q];

    u64 u[KNN];
#pragma unroll
    for (int e = 0; e < KNN; ++e) u[e] = INITK;

#pragma unroll 2
    for (int j = j0; j < j1; ++j) {
        float4 sj = S4[j];                      // lane-varying -> coalesced, L1-resident
        float dd = dist2(sq, sj);
        key_insert(((u64)__float_as_uint(dd) << 32) | (unsigned)j, u);
    }

    // butterfly merge across the 32-lane group: read partner's 8 keys first,
    // then insert (shfl sees pre-insert values)
#pragma unroll
    for (int m = 1; m < 32; m <<= 1) {
        u64 pk[KNN];
#pragma unroll
        for (int e = 0; e < KNN; ++e)
            pk[e] = (u64)__shfl_xor((long long)u[e], m, 32);
#pragma unroll
        for (int e = 0; e < KNN; ++e) key_insert(pk[e], u);
    }

    if (t == 0) {
#pragma unroll
        for (int e = 0; e < KNN; ++e) {
            float d = __uint_as_float((unsigned)(u[e] >> 32));
            KIDX[(size_t)q * KNN + e] = (int)(unsigned)(u[e] & 0xffffffffu);
            KW[(size_t)q * KNN + e]   = expf(-10.f * d);
        }
    }
}

// Fused: gather/aggregate -> emb -> MLP(3 layers) -> out
// Block: 256 threads = 16 rows x 16 out-chunks; activations staged in LDS.
// acc arrays kept <=8 wide and k-loops unroll-bounded to avoid VGPR spills.
__global__ __launch_bounds__(256) void k_fused(const float* __restrict__ x,
                                               const float* __restrict__ H,
                                               const int* __restrict__ KIDX,
                                               const float* __restrict__ KW,
                                               const float* __restrict__ Wo1,
                                               const float* __restrict__ Wo2,
                                               const float* __restrict__ bo2,
                                               const float* __restrict__ W1,
                                               const float* __restrict__ b1,
                                               const float* __restrict__ W2,
                                               const float* __restrict__ b2,
                                               const float* __restrict__ W3,
                                               const float* __restrict__ b3,
                                               float* __restrict__ out) {
    __shared__ float xt[ROWS * IN_F];          // 16x34
    __shared__ float aggt[ROWS * 2 * PDIM];    // 16x44 : [mean(22) | max(22)]
    __shared__ float et[ROWS * IN_F];          // 16x34
    __shared__ float h1t[ROWS * WIDTH];        // 16x126
    __shared__ float h2t[ROWS * WIDTH];        // 16x126  (total 23.3 KB)

    const int tid  = threadIdx.x;
    const int row0 = blockIdx.x * ROWS;
    const int r    = tid >> 4;     // 0..15
    const int c    = tid & 15;     // 0..15
    const int gi   = row0 + r;

    // stage x tile (coalesced)
    for (int t = tid; t < ROWS * IN_F; t += 256)
        xt[t] = x[(size_t)row0 * IN_F + t];

    // gather + aggregate: lane c<11 handles dims {c, c+11}
    if (c < 11) {
        const int p0 = c, p1 = c + 11;
        float s0 = 0.f, s1 = 0.f;
        float m0 = -FLT_MAX, m1 = -FLT_MAX;
#pragma unroll
        for (int k = 0; k < KNN; ++k) {
            int   j = KIDX[(size_t)gi * KNN + k];
            float w = KW[(size_t)gi * KNN + k];
            const float* hr = H + (size_t)j * PDIM;
            float v0 = hr[p0] * w; s0 += v0; m0 = fmaxf(m0, v0);
            float v1 = hr[p1] * w; s1 += v1; m1 = fmaxf(m1, v1);
        }
        aggt[r * 44 + p0] = s0 * 0.125f; aggt[r * 44 + PDIM + p0] = m0;
        aggt[r * 44 + p1] = s1 * 0.125f; aggt[r * 44 + PDIM + p1] = m1;
    }
    __syncthreads();

    // et = x@Wo1 + agg@Wo2 + bo2 ; 3-wide chunks, j0=min(3c,31); overlap
    // lanes write bitwise-identical duplicates (benign)
    {
        const int j0 = (3 * c < 31) ? 3 * c : 31;
        float acc[3] = {0.f, 0.f, 0.f};
        const float* ar = xt + r * IN_F;
#pragma unroll 4
        for (int k = 0; k < IN_F; ++k) {
            float av = ar[k];
            const float* wr = Wo1 + k * IN_F + j0;
#pragma unroll
            for (int jj = 0; jj < 3; ++jj) acc[jj] += av * wr[jj];
        }
        const float* gr = aggt + r * 44;
#pragma unroll 4
        for (int p = 0; p < 2 * PDIM; ++p) {
            float av = gr[p];
            const float* wr = Wo2 + p * IN_F + j0;
#pragma unroll
            for (int jj = 0; jj < 3; ++jj) acc[jj] += av * wr[jj];
        }
#pragma unroll
        for (int jj = 0; jj < 3; ++jj)
            et[r * IN_F + j0 + jj] = acc[jj] + bo2[j0 + jj];
    }
    __syncthreads();

    // h1 = elu(et@W1 + b1) ; 8-wide chunks, j0=min(8c,118)
    {
        const int j0 = (8 * c < 118) ? 8 * c : 118;
        float acc[8] = {0.f, 0.f, 0.f, 0.f, 0.f, 0.f, 0.f, 0.f};
        const float* ar = et + r * IN_F;
#pragma unroll 4
        for (int k = 0; k < IN_F; ++k) {
            float av = ar[k];
            const float* wr = W1 + k * WIDTH + j0;
#pragma unroll
            for (int jj = 0; jj < 8; ++jj) acc[jj] += av * wr[jj];
        }
#pragma unroll
        for (int jj = 0; jj < 8; ++jj) {
            float v = acc[jj] + b1[j0 + jj];
            h1t[r * WIDTH + j0 + jj] = v > 0.f ? v : expm1f(v);
        }
    }
    __syncthreads();

    // h2 = elu(h1@W2 + b2)
    {
        const int j0 = (8 * c < 118) ? 8 * c : 118;
        float acc[8] = {0.f, 0.f, 0.f, 0.f, 0.f, 0.f, 0.f, 0.f};
        const float* ar = h1t + r * WIDTH;
#pragma unroll 4
        for (int k = 0; k < WIDTH; ++k) {
            float av = ar[k];
            const float* wr = W2 + k * WIDTH + j0;
#pragma unroll
            for (int jj = 0; jj < 8; ++jj) acc[jj] += av * wr[jj];
        }
#pragma unroll
        for (int jj = 0; jj < 8; ++jj) {
            float v = acc[jj] + b2[j0 + jj];
            h2t[r * WIDTH + j0 + jj] = v > 0.f ? v : expm1f(v);
        }
    }
    __syncthreads();

    // out = h2@W3 + b3 ; lane c<6 computes one class
    if (c < NCLS) {
        float acc = 0.f;
        const float* ar = h2t + r * WIDTH;
#pragma unroll 4
        for (int k = 0; k < WIDTH; ++k) acc += ar[k] * W3[k * NCLS + c];
        out[(size_t)gi * NCLS + c] = acc + b3[c];
    }
}

extern "C" void kernel_launch(void* const* d_in, const int* in_sizes, int n_in,
                              void* d_out, int out_size, void* d_ws, size_t ws_size,
                              hipStream_t stream) {
    const float* x     = (const float*)d_in[0];
    const int*   batch = (const int*)d_in[1];
    // Only conv index NCONV-1 == 1 affects the output (loop discards earlier)
    const float* Ws  = (const float*)d_in[2] + IN_F * SDIM;
    const float* bs  = (const float*)d_in[3] + SDIM;
    const float* Wh  = (const float*)d_in[4] + IN_F * PDIM;
    const float* bh  = (const float*)d_in[5] + PDIM;
    const float* Wo1 = (const float*)d_in[6] + IN_F * IN_F;
    const float* Wo2 = (const float*)d_in[7] + 2 * PDIM * IN_F;
    const float* bo2 = (const float*)d_in[8] + IN_F;
    const float* W1  = (const float*)d_in[9];
    const float* b1  = (const float*)d_in[10];
    const float* W2  = (const float*)d_in[11];
    const float* b2  = (const float*)d_in[12];
    const float* W3  = (const float*)d_in[13];
    const float* b3  = (const float*)d_in[14];
    float* out = (float*)d_out;

    char* ws = (char*)d_ws;
    int*   ranges = (int*)(ws + OFF_RANGES);
    float* S      = (float*)(ws + OFF_S);
    float* H      = (float*)(ws + OFF_H);
    int*   KIDX   = (int*)(ws + OFF_KIDX);
    float* KW     = (float*)(ws + OFF_KW);

    k_sh<<<dim3(NPT * 32 / 256), dim3(256), 0, stream>>>(x, batch, Ws, bs, Wh, bh, S, H, ranges);
    k_knn<<<dim3(NPT / 8), dim3(256), 0, stream>>>((const float4*)S, batch, ranges, KIDX, KW);
    k_fused<<<dim3(NPT / ROWS), dim3(256), 0, stream>>>(x, H, KIDX, KW, Wo1, Wo2, bo2,
                                                        W1, b1, W2, b2, W3, b3, out);
}

// Round 7
// 127.128 us; speedup vs baseline: 2.0846x; 1.3345x over previous
//
#include <hip/hip_runtime.h>
#include <math.h>
#include <float.h>

// Problem constants (from reference)
#define NPT     16384
#define IN_F    34
#define SDIM    4
#define PDIM    22
#define KNN     8
#define WIDTH   126
#define NCLS    6
#define ROWS    16     // rows per fused-MLP block

typedef unsigned long long u64;

// ---------------- workspace layout (bytes), total ~3 MB ----------------
#define OFF_RANGES 0
#define OFF_S      256
#define OFF_H      (OFF_S  + NPT*SDIM*4)
#define OFF_KIDX   (OFF_H  + NPT*PDIM*4)
#define OFF_KW     (OFF_KIDX + NPT*KNN*4)

// key = (float_bits(d2) << 32) | j : u64 order == lex (d2, idx) order, which is
// exactly jax.lax.top_k's tie-breaking. d2 >= 0 so float bits are monotone.
#define INITK ((((u64)0x7f7fffffu) << 32) | 0xffffffffu)

__device__ __forceinline__ void ce(u64& a, u64& b) {   // a=min, b=max (5 instr)
    bool lt = a < b;
    u64 mn = lt ? a : b;
    u64 mx = lt ? b : a;
    a = mn; b = mx;
}
__device__ __forceinline__ u64 umin64(u64 a, u64 b) { return a < b ? a : b; }

__device__ __forceinline__ void key_insert(u64 key, u64* u) {
#pragma unroll
    for (int t = 0; t < KNN; ++t) {
        bool lt = key < u[t];
        u64 mn = lt ? key  : u[t];
        u64 mx = lt ? u[t] : key;
        u[t] = mn;
        key  = mx;
    }
}

// match reference numerics: rounded squares, sequential sum, no fma
__device__ __forceinline__ float dist2(const float4 a, const float4 b) {
    float d0 = a.x - b.x;
    float d1 = a.y - b.y;
    float d2 = a.z - b.z;
    float d3 = a.w - b.w;
    return __fadd_rn(__fadd_rn(__fadd_rn(__fmul_rn(d0, d0),
                                         __fmul_rn(d1, d1)),
                               __fmul_rn(d2, d2)),
                     __fmul_rn(d3, d3));
}

// 12-CE bitonic sort of a bitonic 8-sequence (m0..m7), ascending result
#define BITONIC8(m0,m1,m2,m3,m4,m5,m6,m7) \
    ce(m0,m4); ce(m1,m5); ce(m2,m6); ce(m3,m7); \
    ce(m0,m2); ce(m1,m3); ce(m4,m6); ce(m5,m7); \
    ce(m0,m1); ce(m2,m3); ce(m4,m5); ce(m6,m7);

// ---------------------------------------------------------
// s = (x@Ws + bs) + 1000*batch ; h = x@Wh + bh  (conv index 1 weights).
// Thread = (row i, slot o): o<4 -> S, o<26 -> H, o==31 -> graph ranges.
__global__ __launch_bounds__(256) void k_sh(const float* __restrict__ x,
                                            const int* __restrict__ batch,
                                            const float* __restrict__ Ws,
                                            const float* __restrict__ bs,
                                            const float* __restrict__ Wh,
                                            const float* __restrict__ bh,
                                            float* __restrict__ S,
                                            float* __restrict__ H,
                                            int* __restrict__ ranges) {
    int t = blockIdx.x * blockDim.x + threadIdx.x;
    int i = t >> 5;
    int o = t & 31;
    if (i >= NPT) return;
    if (o == 31) {  // graph ranges from sorted batch
        int b = batch[i];
        if (i == 0 || batch[i - 1] != b) ranges[b * 2]     = i;
        if (i == NPT - 1 || batch[i + 1] != b) ranges[b * 2 + 1] = i + 1;
        return;
    }
    const float* xr = x + (size_t)i * IN_F;
    if (o < SDIM) {
        float acc = 0.f;
        for (int k = 0; k < IN_F; ++k) acc += xr[k] * Ws[k * SDIM + o];
        S[(size_t)i * SDIM + o] = (acc + bs[o]) + 1000.f * (float)batch[i];
    } else if (o < SDIM + PDIM) {
        int p = o - SDIM;
        float acc = 0.f;
        for (int k = 0; k < IN_F; ++k) acc += xr[k] * Wh[k * PDIM + p];
        H[(size_t)i * PDIM + p] = acc + bh[p];
    }
}

// Fused kNN: 32 lanes per query, INTERLEAVED candidate assignment (lane t
// takes j = gs+t+32*i -> wave loads are 2x512B contiguous). Scan processes 4
// candidates per step: sort-4 network (5 CE) + keep-low-8 bitonic merge
// (4 min + 12 CE) -- exact under the u64 total order, ~40% fewer VALU instr
// than 4 serial 8-deep inserts (round-6 bottleneck). Butterfly merge uses the
// same merge-two-sorted-8 network (8 min + 12 CE) instead of 64 CE.
__global__ __launch_bounds__(256, 4) void k_knn(const float4* __restrict__ S4,
                                                const int* __restrict__ batch,
                                                const int* __restrict__ ranges,
                                                int* __restrict__ KIDX,
                                                float* __restrict__ KW) {
    const int tid = threadIdx.x;
    const int q   = blockIdx.x * 8 + (tid >> 5);
    const int t   = tid & 31;
    const int b   = batch[q];
    const int gs  = ranges[b * 2];
    const int len = ranges[b * 2 + 1] - gs;
    const float4 sq = S4[q];

    u64 u[KNN];
#pragma unroll
    for (int e = 0; e < KNN; ++e) u[e] = INITK;

    const int nfull = len >> 7;     // full 128-candidate (4/lane) batches
    int j = gs + t;
    for (int bb = 0; bb < nfull; ++bb, j += 128) {
        const float4* p = S4 + j;
        float4 s0 = p[0];
        float4 s1 = p[32];
        float4 s2 = p[64];
        float4 s3 = p[96];
        u64 k0 = ((u64)__float_as_uint(dist2(sq, s0)) << 32) | (unsigned)(j);
        u64 k1 = ((u64)__float_as_uint(dist2(sq, s1)) << 32) | (unsigned)(j + 32);
        u64 k2 = ((u64)__float_as_uint(dist2(sq, s2)) << 32) | (unsigned)(j + 64);
        u64 k3 = ((u64)__float_as_uint(dist2(sq, s3)) << 32) | (unsigned)(j + 96);
        // sort 4
        ce(k0, k1); ce(k2, k3); ce(k0, k2); ce(k1, k3); ce(k1, k2);
        // half-cleaner vs sorted u (k padded with +inf -> those slots pass u through)
        u64 m0 = umin64(k0, u[7]);
        u64 m1 = umin64(k1, u[6]);
        u64 m2 = umin64(k2, u[5]);
        u64 m3 = umin64(k3, u[4]);
        u64 m4 = u[3], m5 = u[2], m6 = u[1], m7 = u[0];
        BITONIC8(m0, m1, m2, m3, m4, m5, m6, m7);
        u[0] = m0; u[1] = m1; u[2] = m2; u[3] = m3;
        u[4] = m4; u[5] = m5; u[6] = m6; u[7] = m7;
    }
    // tail: per-lane <=4 singleton inserts (exact; order irrelevant)
    for (int m = (nfull << 7) + t; m < len; m += 32) {
        int jj = gs + m;
        key_insert(((u64)__float_as_uint(dist2(sq, S4[jj])) << 32) | (unsigned)jj, u);
    }

    // butterfly across the 32-lane group: merge two sorted-8 lists per step
#pragma unroll
    for (int mm = 1; mm < 32; mm <<= 1) {
        u64 p0 = (u64)__shfl_xor((long long)u[0], mm, 32);
        u64 p1 = (u64)__shfl_xor((long long)u[1], mm, 32);
        u64 p2 = (u64)__shfl_xor((long long)u[2], mm, 32);
        u64 p3 = (u64)__shfl_xor((long long)u[3], mm, 32);
        u64 p4 = (u64)__shfl_xor((long long)u[4], mm, 32);
        u64 p5 = (u64)__shfl_xor((long long)u[5], mm, 32);
        u64 p6 = (u64)__shfl_xor((long long)u[6], mm, 32);
        u64 p7 = (u64)__shfl_xor((long long)u[7], mm, 32);
        u64 m0 = umin64(u[0], p7);
        u64 m1 = umin64(u[1], p6);
        u64 m2 = umin64(u[2], p5);
        u64 m3 = umin64(u[3], p4);
        u64 m4 = umin64(u[4], p3);
        u64 m5 = umin64(u[5], p2);
        u64 m6 = umin64(u[6], p1);
        u64 m7 = umin64(u[7], p0);
        BITONIC8(m0, m1, m2, m3, m4, m5, m6, m7);
        u[0] = m0; u[1] = m1; u[2] = m2; u[3] = m3;
        u[4] = m4; u[5] = m5; u[6] = m6; u[7] = m7;
    }

    if (t == 0) {
#pragma unroll
        for (int e = 0; e < KNN; ++e) {
            float d = __uint_as_float((unsigned)(u[e] >> 32));
            KIDX[(size_t)q * KNN + e] = (int)(unsigned)(u[e] & 0xffffffffu);
            KW[(size_t)q * KNN + e]   = expf(-10.f * d);
        }
    }
}

// Fused: gather/aggregate -> emb -> MLP(3 layers) -> out
// Block: 256 threads = 16 rows x 16 out-chunks; activations staged in LDS.
// acc arrays kept <=8 wide and k-loops unroll-bounded to avoid VGPR spills.
__global__ __launch_bounds__(256) void k_fused(const float* __restrict__ x,
                                               const float* __restrict__ H,
                                               const int* __restrict__ KIDX,
                                               const float* __restrict__ KW,
                                               const float* __restrict__ Wo1,
                                               const float* __restrict__ Wo2,
                                               const float* __restrict__ bo2,
                                               const float* __restrict__ W1,
                                               const float* __restrict__ b1,
                                               const float* __restrict__ W2,
                                               const float* __restrict__ b2,
                                               const float* __restrict__ W3,
                                               const float* __restrict__ b3,
                                               float* __restrict__ out) {
    __shared__ float xt[ROWS * IN_F];          // 16x34
    __shared__ float aggt[ROWS * 2 * PDIM];    // 16x44 : [mean(22) | max(22)]
    __shared__ float et[ROWS * IN_F];          // 16x34
    __shared__ float h1t[ROWS * WIDTH];        // 16x126
    __shared__ float h2t[ROWS * WIDTH];        // 16x126  (total 23.3 KB)

    const int tid  = threadIdx.x;
    const int row0 = blockIdx.x * ROWS;
    const int r    = tid >> 4;     // 0..15
    const int c    = tid & 15;     // 0..15
    const int gi   = row0 + r;

    // stage x tile (coalesced)
    for (int t = tid; t < ROWS * IN_F; t += 256)
        xt[t] = x[(size_t)row0 * IN_F + t];

    // gather + aggregate: lane c<11 handles dims {c, c+11}
    if (c < 11) {
        const int p0 = c, p1 = c + 11;
        float s0 = 0.f, s1 = 0.f;
        float m0 = -FLT_MAX, m1 = -FLT_MAX;
#pragma unroll
        for (int k = 0; k < KNN; ++k) {
            int   j = KIDX[(size_t)gi * KNN + k];
            float w = KW[(size_t)gi * KNN + k];
            const float* hr = H + (size_t)j * PDIM;
            float v0 = hr[p0] * w; s0 += v0; m0 = fmaxf(m0, v0);
            float v1 = hr[p1] * w; s1 += v1; m1 = fmaxf(m1, v1);
        }
        aggt[r * 44 + p0] = s0 * 0.125f; aggt[r * 44 + PDIM + p0] = m0;
        aggt[r * 44 + p1] = s1 * 0.125f; aggt[r * 44 + PDIM + p1] = m1;
    }
    __syncthreads();

    // et = x@Wo1 + agg@Wo2 + bo2 ; 3-wide chunks, j0=min(3c,31); overlap
    // lanes write bitwise-identical duplicates (benign)
    {
        const int j0 = (3 * c < 31) ? 3 * c : 31;
        float acc[3] = {0.f, 0.f, 0.f};
        const float* ar = xt + r * IN_F;
#pragma unroll 4
        for (int k = 0; k < IN_F; ++k) {
            float av = ar[k];
            const float* wr = Wo1 + k * IN_F + j0;
#pragma unroll
            for (int jj = 0; jj < 3; ++jj) acc[jj] += av * wr[jj];
        }
        const float* gr = aggt + r * 44;
#pragma unroll 4
        for (int p = 0; p < 2 * PDIM; ++p) {
            float av = gr[p];
            const float* wr = Wo2 + p * IN_F + j0;
#pragma unroll
            for (int jj = 0; jj < 3; ++jj) acc[jj] += av * wr[jj];
        }
#pragma unroll
        for (int jj = 0; jj < 3; ++jj)
            et[r * IN_F + j0 + jj] = acc[jj] + bo2[j0 + jj];
    }
    __syncthreads();

    // h1 = elu(et@W1 + b1) ; 8-wide chunks, j0=min(8c,118)
    {
        const int j0 = (8 * c < 118) ? 8 * c : 118;
        float acc[8] = {0.f, 0.f, 0.f, 0.f, 0.f, 0.f, 0.f, 0.f};
        const float* ar = et + r * IN_F;
#pragma unroll 4
        for (int k = 0; k < IN_F; ++k) {
            float av = ar[k];
            const float* wr = W1 + k * WIDTH + j0;
#pragma unroll
            for (int jj = 0; jj < 8; ++jj) acc[jj] += av * wr[jj];
        }
#pragma unroll
        for (int jj = 0; jj < 8; ++jj) {
            float v = acc[jj] + b1[j0 + jj];
            h1t[r * WIDTH + j0 + jj] = v > 0.f ? v : expm1f(v);
        }
    }
    __syncthreads();

    // h2 = elu(h1@W2 + b2)
    {
        const int j0 = (8 * c < 118) ? 8 * c : 118;
        float acc[8] = {0.f, 0.f, 0.f, 0.f, 0.f, 0.f, 0.f, 0.f};
        const float* ar = h1t + r * WIDTH;
#pragma unroll 4
        for (int k = 0; k < WIDTH; ++k) {
            float av = ar[k];
            const float* wr = W2 + k * WIDTH + j0;
#pragma unroll
            for (int jj = 0; jj < 8; ++jj) acc[jj] += av * wr[jj];
        }
#pragma unroll
        for (int jj = 0; jj < 8; ++jj) {
            float v = acc[jj] + b2[j0 + jj];
            h2t[r * WIDTH + j0 + jj] = v > 0.f ? v : expm1f(v);
        }
    }
    __syncthreads();

    // out = h2@W3 + b3 ; lane c<6 computes one class
    if (c < NCLS) {
        float acc = 0.f;
        const float* ar = h2t + r * WIDTH;
#pragma unroll 4
        for (int k = 0; k < WIDTH; ++k) acc += ar[k] * W3[k * NCLS + c];
        out[(size_t)gi * NCLS + c] = acc + b3[c];
    }
}

extern "C" void kernel_launch(void* const* d_in, const int* in_sizes, int n_in,
                              void* d_out, int out_size, void* d_ws, size_t ws_size,
                              hipStream_t stream) {
    const float* x     = (const float*)d_in[0];
    const int*   batch = (const int*)d_in[1];
    // Only conv index NCONV-1 == 1 affects the output (loop discards earlier)
    const float* Ws  = (const float*)d_in[2] + IN_F * SDIM;
    const float* bs  = (const float*)d_in[3] + SDIM;
    const float* Wh  = (const float*)d_in[4] + IN_F * PDIM;
    const float* bh  = (const float*)d_in[5] + PDIM;
    const float* Wo1 = (const float*)d_in[6] + IN_F * IN_F;
    const float* Wo2 = (const float*)d_in[7] + 2 * PDIM * IN_F;
    const float* bo2 = (const float*)d_in[8] + IN_F;
    const float* W1  = (const float*)d_in[9];
    const float* b1  = (const float*)d_in[10];
    const float* W2  = (const float*)d_in[11];
    const float* b2  = (const float*)d_in[12];
    const float* W3  = (const float*)d_in[13];
    const float* b3  = (const float*)d_in[14];
    float* out = (float*)d_out;

    char* ws = (char*)d_ws;
    int*   ranges = (int*)(ws + OFF_RANGES);
    float* S      = (float*)(ws + OFF_S);
    float* H      = (float*)(ws + OFF_H);
    int*   KIDX   = (int*)(ws + OFF_KIDX);
    float* KW     = (float*)(ws + OFF_KW);

    k_sh<<<dim3(NPT * 32 / 256), dim3(256), 0, stream>>>(x, batch, Ws, bs, Wh, bh, S, H, ranges);
    k_knn<<<dim3(NPT / 8), dim3(256), 0, stream>>>((const float4*)S, batch, ranges, KIDX, KW);
    k_fused<<<dim3(NPT / ROWS), dim3(256), 0, stream>>>(x, H, KIDX, KW, Wo1, Wo2, bo2,
                                                        W1, b1, W2, b2, W3, b3, out);
}